// Round 11
// baseline (424.192 us; speedup 1.0000x reference)
//
#include <hip/hip_runtime.h>

#define HID 128
#define LN_EPS 1e-5f

typedef __attribute__((ext_vector_type(8))) short bf16x8;
typedef __attribute__((ext_vector_type(4))) float f32x4;

__device__ __forceinline__ ushort f2bf(float v) {
  union { float f; uint u; } x; x.f = v;
  uint r = x.u + 0x7fffu + ((x.u >> 16) & 1u);   // RNE
  return (ushort)(r >> 16);
}
__device__ __forceinline__ float bf2f(ushort u) {
  union { uint u; float f; } x; x.u = (uint)u << 16; return x.f;
}

// ---------------- graph preprocessing ----------------

__global__ void k_init(int* __restrict__ cnt, int n) {
  int i = blockIdx.x * 256 + threadIdx.x;
  if (i < n) cnt[i] = 0;
}

// counts AND records each edge's rank within its dst list (atomic return value)
__global__ void k_count(const int* __restrict__ dst, int* __restrict__ cnt,
                        int* __restrict__ rank, int E) {
  int e = blockIdx.x * 256 + threadIdx.x;
  if (e < E) rank[e] = atomicAdd(&cnt[dst[e]], 1);
}

// block sums for scan + dinv (folded in: reads cnt anyway)
__global__ void k_bsum(const int* __restrict__ cnt, int* __restrict__ bsum,
                       float* __restrict__ dinv, int n) {
  __shared__ int red[256];
  int b = blockIdx.x, t = threadIdx.x;
  int i = b * 512 + t * 2;
  int c0 = (i < n) ? cnt[i] : 0;
  int c1 = (i + 1 < n) ? cnt[i + 1] : 0;
  if (i < n) dinv[i] = rsqrtf((float)c0 + 1.0f);       // +1 = self loop
  if (i + 1 < n) dinv[i + 1] = rsqrtf((float)c1 + 1.0f);
  red[t] = c0 + c1;
  __syncthreads();
  for (int off = 128; off > 0; off >>= 1) {
    if (t < off) red[t] += red[t + off];
    __syncthreads();
  }
  if (t == 0) bsum[b] = red[0];
}

__global__ void k_bscan(int* __restrict__ bsum, int nb) {
  __shared__ int buf[1024];
  int t = threadIdx.x;
  int v = (t < nb) ? bsum[t] : 0;
  buf[t] = v;
  __syncthreads();
  for (int off = 1; off < 1024; off <<= 1) {
    int u = (t >= off) ? buf[t - off] : 0;
    __syncthreads();
    buf[t] += u;
    __syncthreads();
  }
  if (t < nb) bsum[t] = buf[t] - v;   // exclusive
}

__global__ void k_rowstart(const int* __restrict__ cnt, const int* __restrict__ bsum,
                           int* __restrict__ row_start, int n) {
  __shared__ int buf[256];
  int b = blockIdx.x, t = threadIdx.x;
  int i = b * 512 + t * 2;
  int c0 = (i < n) ? cnt[i] : 0;
  int c1 = (i + 1 < n) ? cnt[i + 1] : 0;
  int s = c0 + c1;
  buf[t] = s;
  __syncthreads();
  int mine = s;
  for (int off = 1; off < 256; off <<= 1) {
    int u = (t >= off) ? buf[t - off] : 0;
    __syncthreads();
    buf[t] += u;
    __syncthreads();
  }
  int ex = buf[t] - mine + bsum[b];
  if (i < n) row_start[i] = ex;
  if (i + 1 < n) row_start[i + 1] = ex + c0;
}

// atomic-free scatter: one 8B record per edge at row_start[dst] + rank[e]
__global__ void k_scatter(const int* __restrict__ src, const int* __restrict__ dst,
                          const int* __restrict__ row_start, const int* __restrict__ rank,
                          const float* __restrict__ dinv,
                          uint2* __restrict__ rec, int E) {
  int e = blockIdx.x * 256 + threadIdx.x;
  if (e < E) {
    int d = dst[e], s = src[e];
    int pos = row_start[d] + rank[e];
    union { float f; uint u; } w; w.f = dinv[s] * dinv[d];
    rec[pos] = make_uint2((uint)s, w.u);
  }
}

// ---------------- weight prep: bf16, MFMA-fragment-ordered ----------------
// Fragment layout: frag[(n*KS + ks)*512 + lane*8 + j] = W^T-element for
//   k = ks*32 + (lane>>4)*8 + j,  col = n*16 + (lane&15)
__global__ void k_prep_w(const float* __restrict__ lin_in_w,
                         const float* __restrict__ conv_w, const float* __restrict__ lin_w,
                         const float* __restrict__ conv_b, const float* __restrict__ lin_b,
                         ushort* __restrict__ wt_in, ushort* __restrict__ wt_l,
                         float* __restrict__ bsum, int L) {
  int tid = blockIdx.x * 256 + threadIdx.x;
  int total = L * 128 * 256;
  if (tid < total) {
    int l = tid >> 15;              // /32768
    int idx = tid & 32767;
    int n = idx >> 12;              // 8 col-blocks
    int r = idx & 4095;
    int ks = r >> 9;                // 8 k-steps (K=256)
    int r2 = r & 511;
    int lane = r2 >> 3;
    int j = r2 & 7;
    int k2 = ks * 32 + (lane >> 4) * 8 + j;
    int c = n * 16 + (lane & 15);
    float v = (k2 < 128) ? conv_w[((size_t)l * 128 + k2) * 128 + c]
                         : lin_w[((size_t)l * 128 + (k2 - 128)) * 128 + c];
    wt_l[tid] = f2bf(v);
  }
  if (tid < 128 * 128) {
    int n = tid >> 11;              // 8 col-blocks
    int r = tid & 2047;
    int ks = r >> 9;                // 4 k-steps (K=128)
    int r2 = r & 511;
    int lane = r2 >> 3;
    int j = r2 & 7;
    int k = ks * 32 + (lane >> 4) * 8 + j;
    int c = n * 16 + (lane & 15);
    wt_in[tid] = f2bf(lin_in_w[k * 128 + c]);
  }
  if (tid < L * 128) bsum[tid] = conv_b[tid] + lin_b[tid];
}

// ---------------- aggregation: s = D^-1/2 (A+I) D^-1/2 x  (bf16 in/out) ----------------
// TWO SEQUENTIAL DISPATCHES (colh = 0, 1), each gathering one 128B half-row.
// Per-pass hot working set = N*128B = 6.4MB (vs 12.8) -> higher per-XCD L2 hit rate,
// less L3-fill traffic (the measured ~2.2 TB/s fill ceiling). Unlike the failed r8
// interleaved chunking, passes are GLOBALLY sequential and rec is only re-read 2x.
// Wave: 2 edges x 32 lanes (4B = 2 cols each); 16 edges in flight per unroll.
__global__ void k_agg(const ushort* __restrict__ X, const int* __restrict__ row_start,
                      const int* __restrict__ cnt, const float* __restrict__ dinv,
                      const uint2* __restrict__ rec, ushort* __restrict__ Sout,
                      int n, int colh) {
  int node = blockIdx.x * 4 + (threadIdx.x >> 6);
  if (node >= n) return;
  const int lane = threadIdx.x & 63;
  const int e2 = lane >> 5;          // which of 2 edges per load
  const int cg = lane & 31;          // col pair within half-row
  const int colb = colh * 64 + cg * 2;

  float ax = 0.f, ay = 0.f;
  const int start = row_start[node];
  const int m = cnt[node];
  const int last = start + m - 1;
  const ulong* recq = reinterpret_cast<const ulong*>(rec);

  for (int e = 0; e < m; e += 16) {
    ulong q[8];
#pragma unroll
    for (int j = 0; j < 8; j++) q[j] = recq[min(start + e + 2 * j + e2, last)];
    uint u[8];
#pragma unroll
    for (int j = 0; j < 8; j++)
      u[j] = *reinterpret_cast<const uint*>(X + (size_t)(uint)q[j] * HID + colb);
#pragma unroll
    for (int j = 0; j < 8; j++) {
      union { uint u; float f; } w;
      w.u = (e + 2 * j + e2 < m) ? (uint)(q[j] >> 32) : 0u;
      ax = fmaf(w.f, bf2f((ushort)(u[j] & 0xffff)), ax);
      ay = fmaf(w.f, bf2f((ushort)(u[j] >> 16)), ay);
    }
  }
  ax += __shfl_xor(ax, 32);
  ay += __shfl_xor(ay, 32);
  if (e2 == 0) {
    float dv = dinv[node];
    float d2 = dv * dv;
    uint v = *reinterpret_cast<const uint*>(X + (size_t)node * HID + colb);
    ax = fmaf(d2, bf2f((ushort)(v & 0xffff)), ax);
    ay = fmaf(d2, bf2f((ushort)(v >> 16)), ay);
    *reinterpret_cast<uint*>(Sout + (size_t)node * HID + colb) =
        (uint)f2bf(ax) | ((uint)f2bf(ay) << 16);
  }
}

// ---------------- MFMA GEMM kernels ----------------
// per block: 4 waves, 16 rows each; per wave: full 128 output cols.
// A-frag: lane holds A[r0 + (l&15)][ks*32 + (l>>4)*8 .. +7]
// B-frag: from fragment-ordered WtF, LDS-staged in 16KB quarters (n-pairs) with
//   register prefetch -> B-read L2 traffic 200MB -> 50MB per layer.
// C: row=(l>>4)*4+q, col=n*16+(l&15) -> LDS transpose for coalesced epilogue

__global__ void __launch_bounds__(256, 2)
k_gemm_in(const float* __restrict__ Xin, const ushort* __restrict__ WtF,
          const float* __restrict__ bias, ushort* __restrict__ Xout, int nrows) {
  __shared__ float lds[4 * 16 * 132];
  const int tid = threadIdx.x;
  const int wid = tid >> 6, lane = tid & 63;
  const int lr = lane & 15, lg = lane >> 4;
  const int r0 = blockIdx.x * 64 + wid * 16;
  const int arow = r0 + lr;
  const bool rowok = arow < nrows;

  bf16x8 a[4];
  {
    const float* xp = Xin + (size_t)arow * HID + lg * 8;
#pragma unroll
    for (int ks = 0; ks < 4; ks++) {
      bf16x8 t;
#pragma unroll
      for (int i = 0; i < 8; i++) t[i] = 0;
      if (rowok) {
        float4 u0 = *reinterpret_cast<const float4*>(xp + ks * 32);
        float4 u1 = *reinterpret_cast<const float4*>(xp + ks * 32 + 4);
        t[0] = (short)f2bf(u0.x); t[1] = (short)f2bf(u0.y);
        t[2] = (short)f2bf(u0.z); t[3] = (short)f2bf(u0.w);
        t[4] = (short)f2bf(u1.x); t[5] = (short)f2bf(u1.y);
        t[6] = (short)f2bf(u1.z); t[7] = (short)f2bf(u1.w);
      }
      a[ks] = t;
    }
  }

  f32x4 acc[8];
#pragma unroll
  for (int n = 0; n < 8; n++) acc[n] = f32x4{0.f, 0.f, 0.f, 0.f};

  const ushort* wb = WtF + lane * 8;
#pragma unroll
  for (int n = 0; n < 8; n++)
#pragma unroll
    for (int ks = 0; ks < 4; ks++) {
      bf16x8 b = *reinterpret_cast<const bf16x8*>(wb + (n * 4 + ks) * 512);
      acc[n] = __builtin_amdgcn_mfma_f32_16x16x32_bf16(a[ks], b, acc[n], 0, 0, 0);
    }

  float* T = lds + wid * (16 * 132);
#pragma unroll
  for (int n = 0; n < 8; n++)
#pragma unroll
    for (int q = 0; q < 4; q++)
      T[(lg * 4 + q) * 132 + n * 16 + lr] = acc[n][q];

  const int c0 = lg * 32;
  const float* Trow = T + lr * 132 + c0;
  const int orow = r0 + lr;
  if (orow < nrows) {
    ushort* xo = Xout + (size_t)orow * HID + c0;
    uint pk[16];
#pragma unroll
    for (int j = 0; j < 8; j++) {
      float4 t = *reinterpret_cast<const float4*>(Trow + j * 4);
      float4 b4 = *reinterpret_cast<const float4*>(bias + c0 + j * 4);
      float o0 = t.x + b4.x, o1 = t.y + b4.y, o2 = t.z + b4.z, o3 = t.w + b4.w;
      pk[j * 2 + 0] = (uint)f2bf(o0) | ((uint)f2bf(o1) << 16);
      pk[j * 2 + 1] = (uint)f2bf(o2) | ((uint)f2bf(o3) << 16);
    }
#pragma unroll
    for (int j = 0; j < 4; j++)
      *reinterpret_cast<uint4*>(xo + j * 8) =
          make_uint4(pk[j * 4 + 0], pk[j * 4 + 1], pk[j * 4 + 2], pk[j * 4 + 3]);
  }
}

__global__ void __launch_bounds__(256, 2)
k_layer(const ushort* __restrict__ S, const ushort* __restrict__ Xin,
        ushort* __restrict__ Xout,
        const ushort* __restrict__ WtF, const float* __restrict__ bsum,
        const float* __restrict__ gamma, const float* __restrict__ beta, int nrows,
        int last, const ushort* __restrict__ jk1, const ushort* __restrict__ jk2,
        float* __restrict__ out) {
  __shared__ ushort wlds[8192];       // 16KB: one n-pair (2 n-blocks x 8 ks x 512)
  __shared__ float lds[4 * 16 * 132]; // 33.8KB transpose buffer; total 49.8KB -> 2 blk/CU
  const int tid = threadIdx.x;
  const int wid = tid >> 6, lane = tid & 63;
  const int lr = lane & 15, lg = lane >> 4;
  const int r0 = blockIdx.x * 64 + wid * 16;
  const int arow = r0 + lr;
  const bool rowok = arow < nrows;

  bf16x8 a[8];
  {
    const ushort* sp = S + (size_t)arow * HID + lg * 8;
    const ushort* xp = Xin + (size_t)arow * HID + lg * 8;
    bf16x8 z;
#pragma unroll
    for (int i = 0; i < 8; i++) z[i] = 0;
#pragma unroll
    for (int ks = 0; ks < 4; ks++)
      a[ks] = rowok ? *reinterpret_cast<const bf16x8*>(sp + ks * 32) : z;
#pragma unroll
    for (int ks = 0; ks < 4; ks++)
      a[4 + ks] = rowok ? *reinterpret_cast<const bf16x8*>(xp + ks * 32) : z;
  }

  f32x4 acc[8];
#pragma unroll
  for (int n = 0; n < 8; n++) acc[n] = f32x4{0.f, 0.f, 0.f, 0.f};

  // quarter-staged B: prefetch quarter np+1 to regs while MFMA'ing quarter np
  const uint4* gW = reinterpret_cast<const uint4*>(WtF);
  uint4* ldsW = reinterpret_cast<uint4*>(wlds);
  uint4 stg[4];
#pragma unroll
  for (int p = 0; p < 4; p++) stg[p] = gW[p * 256 + tid];
#pragma unroll
  for (int np = 0; np < 4; np++) {
#pragma unroll
    for (int p = 0; p < 4; p++) ldsW[p * 256 + tid] = stg[p];
    __syncthreads();
    if (np < 3) {
#pragma unroll
      for (int p = 0; p < 4; p++) stg[p] = gW[(np + 1) * 1024 + p * 256 + tid];
    }
#pragma unroll
    for (int nn = 0; nn < 2; nn++) {
      const int n = np * 2 + nn;
      const ushort* wb2 = wlds + nn * 8 * 512 + lane * 8;
#pragma unroll
      for (int ks = 0; ks < 8; ks++) {
        bf16x8 b = *reinterpret_cast<const bf16x8*>(wb2 + ks * 512);
        acc[n] = __builtin_amdgcn_mfma_f32_16x16x32_bf16(a[ks], b, acc[n], 0, 0, 0);
      }
    }
    __syncthreads();
  }

  float* T = lds + wid * (16 * 132);
#pragma unroll
  for (int n = 0; n < 8; n++)
#pragma unroll
    for (int q = 0; q < 4; q++)
      T[(lg * 4 + q) * 132 + n * 16 + lr] = acc[n][q];

  // epilogue: lane handles row lr, cols [c0, c0+32)
  const int c0 = lg * 32;
  const float* Trow = T + lr * 132 + c0;
  float v[32];
  float sum = 0.f, sq = 0.f;
#pragma unroll
  for (int j = 0; j < 8; j++) {
    float4 t = *reinterpret_cast<const float4*>(Trow + j * 4);
    float4 b4 = *reinterpret_cast<const float4*>(bsum + c0 + j * 4);
    float x0 = t.x + b4.x, x1 = t.y + b4.y, x2 = t.z + b4.z, x3 = t.w + b4.w;
    v[j * 4 + 0] = x0; v[j * 4 + 1] = x1; v[j * 4 + 2] = x2; v[j * 4 + 3] = x3;
    sum += (x0 + x1) + (x2 + x3);
    sq = fmaf(x0, x0, sq); sq = fmaf(x1, x1, sq);
    sq = fmaf(x2, x2, sq); sq = fmaf(x3, x3, sq);
  }
  sum += __shfl_xor(sum, 16); sq += __shfl_xor(sq, 16);
  sum += __shfl_xor(sum, 32); sq += __shfl_xor(sq, 32);
  const float mean = sum * (1.f / 128.f);
  const float rstd = rsqrtf(sq * (1.f / 128.f) - mean * mean + LN_EPS);

  const int orow = r0 + lr;
  if (orow < nrows) {
    float o[32];
#pragma unroll
    for (int j = 0; j < 8; j++) {
      float4 g4 = *reinterpret_cast<const float4*>(gamma + c0 + j * 4);
      float4 b4 = *reinterpret_cast<const float4*>(beta + c0 + j * 4);
      o[j * 4 + 0] = fmaxf(fmaf((v[j * 4 + 0] - mean) * rstd, g4.x, b4.x), 0.f);
      o[j * 4 + 1] = fmaxf(fmaf((v[j * 4 + 1] - mean) * rstd, g4.y, b4.y), 0.f);
      o[j * 4 + 2] = fmaxf(fmaf((v[j * 4 + 2] - mean) * rstd, g4.z, b4.z), 0.f);
      o[j * 4 + 3] = fmaxf(fmaf((v[j * 4 + 3] - mean) * rstd, g4.w, b4.w), 0.f);
    }
    if (!last) {
      ushort* xo = Xout + (size_t)orow * HID + c0;
      uint pk[16];
#pragma unroll
      for (int j = 0; j < 16; j++)
        pk[j] = (uint)f2bf(o[j * 2]) | ((uint)f2bf(o[j * 2 + 1]) << 16);
#pragma unroll
      for (int j = 0; j < 4; j++)
        *reinterpret_cast<uint4*>(xo + j * 8) =
            make_uint4(pk[j * 4 + 0], pk[j * 4 + 1], pk[j * 4 + 2], pk[j * 4 + 3]);
    } else {
      // fused JK: out = x1 + x2 + x3 (f32), skip Xout entirely
      const ushort* p1 = jk1 + (size_t)orow * HID + c0;
      const ushort* p2 = jk2 + (size_t)orow * HID + c0;
      float* op = out + (size_t)orow * HID + c0;
#pragma unroll
      for (int j = 0; j < 4; j++) {
        uint4 u1 = *reinterpret_cast<const uint4*>(p1 + j * 8);
        uint4 u2 = *reinterpret_cast<const uint4*>(p2 + j * 8);
        const uint w1[4] = {u1.x, u1.y, u1.z, u1.w};
        const uint w2[4] = {u2.x, u2.y, u2.z, u2.w};
        float r[8];
#pragma unroll
        for (int q = 0; q < 4; q++) {
          r[q * 2 + 0] = o[j * 8 + q * 2 + 0] +
                         bf2f((ushort)(w1[q] & 0xffff)) + bf2f((ushort)(w2[q] & 0xffff));
          r[q * 2 + 1] = o[j * 8 + q * 2 + 1] +
                         bf2f((ushort)(w1[q] >> 16)) + bf2f((ushort)(w2[q] >> 16));
        }
        *reinterpret_cast<float4*>(op + j * 8) = make_float4(r[0], r[1], r[2], r[3]);
        *reinterpret_cast<float4*>(op + j * 8 + 4) = make_float4(r[4], r[5], r[6], r[7]);
      }
    }
  }
}

// ---------------- launcher ----------------

extern "C" void kernel_launch(void* const* d_in, const int* in_sizes, int n_in,
                              void* d_out, int out_size, void* d_ws, size_t ws_size,
                              hipStream_t stream) {
  const float* x_in     = (const float*)d_in[0];
  const int*   edge     = (const int*)d_in[1];
  const float* lin_in_w = (const float*)d_in[2];
  const float* lin_in_b = (const float*)d_in[3];
  const float* conv_w   = (const float*)d_in[4];
  const float* conv_b   = (const float*)d_in[5];
  const float* lin_w    = (const float*)d_in[6];
  const float* lin_b    = (const float*)d_in[7];
  const float* ln_g     = (const float*)d_in[8];
  const float* ln_b     = (const float*)d_in[9];

  int N = in_sizes[0] / HID;
  int E = in_sizes[1] / 2;
  int L = in_sizes[4] / (HID * HID);

  const int* src = edge;
  const int* dst = edge + E;

  char* ws = (char*)d_ws;
  size_t off = 0;
  auto alloc = [&](size_t bytes) -> void* {
    void* p = (void*)(ws + off);
    off += (bytes + 255) & ~(size_t)255;
    return p;
  };
  int*    cnt       = (int*)alloc((size_t)N * 4);
  int*    rank      = (int*)alloc((size_t)E * 4);
  int*    row_start = (int*)alloc((size_t)N * 4);
  float*  dinv      = (float*)alloc((size_t)N * 4);
  int*    blocksum  = (int*)alloc(4096);
  uint2*  rec       = (uint2*)alloc((size_t)E * 8);
  ushort* xb0       = (ushort*)alloc((size_t)N * HID * 2);
  ushort* xb1       = (ushort*)alloc((size_t)N * HID * 2);
  ushort* xb2       = (ushort*)alloc((size_t)N * HID * 2);
  ushort* sbuf      = (ushort*)alloc((size_t)N * HID * 2);
  ushort* wt_in     = (ushort*)alloc((size_t)128 * 128 * 2);
  ushort* wt_l      = (ushort*)alloc((size_t)L * 128 * 256 * 2);
  float*  bsum      = (float*)alloc((size_t)L * 128 * 4);
  (void)ws_size; (void)n_in; (void)out_size;

  int nb_n = (N + 255) / 256;
  int nb_e = (E + 255) / 256;
  int nbs  = (N + 511) / 512;
  int nb_g = (N + 63) / 64;
  int nb_w = (L * 128 * 256 + 255) / 256;
  int nb_a = (N + 3) / 4;

  k_init<<<nb_n, 256, 0, stream>>>(cnt, N);
  k_count<<<nb_e, 256, 0, stream>>>(dst, cnt, rank, E);
  k_bsum<<<nbs, 256, 0, stream>>>(cnt, blocksum, dinv, N);
  k_bscan<<<1, 1024, 0, stream>>>(blocksum, nbs);
  k_rowstart<<<nbs, 256, 0, stream>>>(cnt, blocksum, row_start, N);
  k_scatter<<<nb_e, 256, 0, stream>>>(src, dst, row_start, rank, dinv, rec, E);
  k_prep_w<<<nb_w, 256, 0, stream>>>(lin_in_w, conv_w, lin_w, conv_b, lin_b,
                                     wt_in, wt_l, bsum, L);

  k_gemm_in<<<nb_g, 256, 0, stream>>>(x_in, wt_in, lin_in_b, xb0, N);

  // rotate: layer i reads xprev, writes xcur; last layer fuses JK sum into f32 out
  ushort* xin_b[3]  = {xb0, xb1, xb2};
  ushort* xout_b[3] = {xb1, xb2, xb0};
  for (int i = 0; i < L; i++) {
    k_agg<<<nb_a, 256, 0, stream>>>(xin_b[i], row_start, cnt, dinv, rec, sbuf, N, 0);
    k_agg<<<nb_a, 256, 0, stream>>>(xin_b[i], row_start, cnt, dinv, rec, sbuf, N, 1);
    int last = (i == L - 1) ? 1 : 0;
    k_layer<<<nb_g, 256, 0, stream>>>(sbuf, xin_b[i], xout_b[i],
        wt_l + (size_t)i * 128 * 256, bsum + (size_t)i * 128,
        ln_g + (size_t)i * HID, ln_b + (size_t)i * HID, N,
        last, xb1, xb2, (float*)d_out);
  }
}